// Round 2
// baseline (865.842 us; speedup 1.0000x reference)
//
#include <hip/hip_runtime.h>

// MLPPredictor: score[e] = relu(h[src[e]]@W1u + h[dst[e]]@W1v + b1) @ W2 + b2
// Factorization: PQ = h @ [W1u|W1v] (+b1 folded into Q half), bf16, in d_ws.
// Stage A: MFMA GEMM with hi/lo split of h (near-fp32 accuracy).
// Stage B: per-edge gather directly into MFMA A-fragment layout (no LDS hid),
//          W2 as packed B-fragments in LDS (conflict-free b128 reads).

typedef short bf16x8 __attribute__((ext_vector_type(8)));   // 8 bf16 = 4 VGPR
typedef float f32x4 __attribute__((ext_vector_type(4)));

#define DIM 128
#define C_OUT 86
#define NPAD 96      // 86 padded to 6 x 16 MFMA col-tiles

__device__ __forceinline__ float bf2f(unsigned short u) {
    unsigned int x = ((unsigned int)u) << 16;
    float f;
    __builtin_memcpy(&f, &x, 4);
    return f;
}
__device__ __forceinline__ unsigned short f2bf(float f) {
    unsigned int x;
    __builtin_memcpy(&x, &f, 4);
    x = x + 0x7fffu + ((x >> 16) & 1u);   // round-to-nearest-even
    return (unsigned short)(x >> 16);
}

// ---------------- Stage A: PQ[n][0:128]=h@W1u, PQ[n][128:256]=h@W1v + b1 ----
// grid (512, 2): y = N-half. W1 half packed in LDS as B-fragments.
// A-frags from global h (fp32 -> hi/lo bf16 split), 2 MFMAs per k-step.
__global__ __launch_bounds__(256, 5) void node_gemm_kernel(
    const float* __restrict__ h, const float* __restrict__ W1,
    const float* __restrict__ b1,
    unsigned short* __restrict__ PQ, int n_nodes)
{
    __shared__ unsigned short W1p[8 * 4 * 64 * 8];   // [nt][kt][lane][j] = 32 KB
    const int t = threadIdx.x;
    const int half = blockIdx.y;

    // pack: element (k, jn) -> B[k][n=half*128+jn]; frag lane = quad*16 + (jn&15)
    for (int i = t; i < 128 * 128; i += 256) {
        int k = i >> 7;
        int jn = i & 127;                            // coalesced over jn
        float v = W1[(size_t)(half * 128 + k) * 128 + jn];
        int nt = jn >> 4, m = jn & 15;
        int kt = k >> 5, quad = (k >> 3) & 3, jj = k & 7;
        W1p[(((nt * 4 + kt) * 64) + quad * 16 + m) * 8 + jj] = f2bf(v);
    }
    __syncthreads();

    const int lane = t & 63;
    const int wv = t >> 6;
    const int m = lane & 15;
    const int quad = lane >> 4;
    const bf16x8* bp = (const bf16x8*)W1p;

    float bias[8];
#pragma unroll
    for (int nt = 0; nt < 8; ++nt) bias[nt] = half ? b1[nt * 16 + m] : 0.f;

    for (int m0 = blockIdx.x * 64; m0 < n_nodes; m0 += gridDim.x * 64) {
        int row = m0 + wv * 16 + m;
        int rowc = row < n_nodes ? row : n_nodes - 1;
        const float* hrow = h + (size_t)rowc * DIM;
        bf16x8 ahi[4], alo[4];
#pragma unroll
        for (int kt = 0; kt < 4; ++kt) {
            float4 a0 = *(const float4*)(hrow + kt * 32 + quad * 8);
            float4 a1 = *(const float4*)(hrow + kt * 32 + quad * 8 + 4);
            float a[8] = {a0.x, a0.y, a0.z, a0.w, a1.x, a1.y, a1.z, a1.w};
#pragma unroll
            for (int j = 0; j < 8; ++j) {
                unsigned short hb = f2bf(a[j]);
                ahi[kt][j] = (short)hb;
                alo[kt][j] = (short)f2bf(a[j] - bf2f(hb));
            }
        }
#pragma unroll
        for (int nt = 0; nt < 8; ++nt) {
            f32x4 acc = {0.f, 0.f, 0.f, 0.f};
#pragma unroll
            for (int kt = 0; kt < 4; ++kt) {
                bf16x8 bf = bp[(nt * 4 + kt) * 64 + lane];
                acc = __builtin_amdgcn_mfma_f32_16x16x32_bf16(ahi[kt], bf, acc, 0, 0, 0);
                acc = __builtin_amdgcn_mfma_f32_16x16x32_bf16(alo[kt], bf, acc, 0, 0, 0);
            }
            int rbase = m0 + wv * 16 + quad * 4;
            int col = half * 128 + nt * 16 + m;
#pragma unroll
            for (int r = 0; r < 4; ++r) {
                int ro = rbase + r;
                if (ro < n_nodes)
                    PQ[(size_t)ro * 256 + col] = f2bf(acc[r] + bias[nt]);
            }
        }
        // W1p is read-only after setup: no barrier needed between m-tiles
    }
}

// ---------------- Stage B: per-edge MLP, gather straight into A-frags --------
__global__ __launch_bounds__(256, 6) void edge_mlp_kernel(
    const unsigned short* __restrict__ PQ,
    const float* __restrict__ W2,
    const float* __restrict__ b2,
    const int* __restrict__ src,
    const int* __restrict__ dst,
    float* __restrict__ out,
    int n_edges)
{
    __shared__ unsigned short W2p[6 * 4 * 64 * 8];   // packed B-frags = 24 KB
    const int t = threadIdx.x;

    // pack W2 (128 x 86 fp32, row-major) -> frag layout; coalesced over n
    for (int i = t; i < 128 * 128; i += 256) {
        int k = i >> 7;
        int n = i & 127;
        if (n < NPAD) {
            float v = (n < C_OUT) ? W2[(size_t)k * C_OUT + n] : 0.f;
            int nt = n >> 4, mm = n & 15;
            int kt = k >> 5, qq = (k >> 3) & 3, jj = k & 7;
            W2p[(((nt * 4 + kt) * 64) + qq * 16 + mm) * 8 + jj] = f2bf(v);
        }
    }
    __syncthreads();

    const int lane = t & 63;
    const int wv = t >> 6;
    const int m = lane & 15;
    const int quad = lane >> 4;
    const bf16x8* bp = (const bf16x8*)W2p;

    float bias[6];
#pragma unroll
    for (int nt = 0; nt < 6; ++nt) {
        int col = nt * 16 + m;
        bias[nt] = (col < C_OUT) ? b2[col] : 0.f;
    }

    const int last = n_edges - 1;
    for (int c = blockIdx.x; c * 64 < n_edges; c += gridDim.x) {
        const int e0 = c * 64;
        int e = e0 + wv * 16 + m;
        int ec = e <= last ? e : last;
        int s = src[ec];
        int d = dst[ec];
        const bf16x8* Pp = (const bf16x8*)(PQ + (size_t)s * 256);
        const bf16x8* Qp = (const bf16x8*)(PQ + (size_t)d * 256 + 128);

        bf16x8 af[4];
#pragma unroll
        for (int kt = 0; kt < 4; ++kt) {
            bf16x8 p = Pp[kt * 4 + quad];
            bf16x8 q = Qp[kt * 4 + quad];
#pragma unroll
            for (int j = 0; j < 8; ++j) {
                float x = bf2f((unsigned short)p[j]) + bf2f((unsigned short)q[j]);
                af[kt][j] = (short)f2bf(fmaxf(x, 0.f));
            }
        }

#pragma unroll
        for (int nt = 0; nt < 6; ++nt) {
            f32x4 acc = {0.f, 0.f, 0.f, 0.f};
#pragma unroll
            for (int kt = 0; kt < 4; ++kt)
                acc = __builtin_amdgcn_mfma_f32_16x16x32_bf16(af[kt], bp[(nt * 4 + kt) * 64 + lane], acc, 0, 0, 0);
            int col = nt * 16 + m;
            if (col < C_OUT) {
                float bb = bias[nt];
                int ebase = e0 + wv * 16 + quad * 4;
#pragma unroll
                for (int r = 0; r < 4; ++r) {
                    int eo = ebase + r;
                    if (eo < n_edges)
                        out[(size_t)eo * C_OUT + col] = acc[r] + bb;
                }
            }
        }
        // W2p read-only: no barrier in the chunk loop
    }
}

extern "C" void kernel_launch(void* const* d_in, const int* in_sizes, int n_in,
                              void* d_out, int out_size, void* d_ws, size_t ws_size,
                              hipStream_t stream) {
    const float* h  = (const float*)d_in[0];
    const float* W1 = (const float*)d_in[1];
    const float* b1 = (const float*)d_in[2];
    const float* W2 = (const float*)d_in[3];
    const float* b2 = (const float*)d_in[4];
    const int* src  = (const int*)d_in[5];
    const int* dst  = (const int*)d_in[6];
    float* out = (float*)d_out;
    const int n_nodes = in_sizes[0] / DIM;      // 100000
    const int n_edges = in_sizes[5];            // 1000000
    unsigned short* PQ = (unsigned short*)d_ws; // 100000*256 bf16 = 51.2 MB

    node_gemm_kernel<<<dim3(512, 2), 256, 0, stream>>>(h, W1, b1, PQ, n_nodes);
    edge_mlp_kernel<<<dim3(2048), 256, 0, stream>>>(PQ, W2, b2, src, dst, out, n_edges);
}